// Round 3
// baseline (205.961 us; speedup 1.0000x reference)
//
#include <hip/hip_runtime.h>
#include <math.h>

#define BN 4096
#define DD 128
#define NCLS 64
#define PSPLIT 16

typedef __attribute__((ext_vector_type(8))) short short8;
typedef __attribute__((ext_vector_type(4))) float f32x4;

__device__ __forceinline__ unsigned short f2bf(float f) {
    unsigned int u = __float_as_uint(f);
    u += 0x7FFFu + ((u >> 16) & 1u);   // RNE; inputs are finite normals
    return (unsigned short)(u >> 16);
}

__device__ __forceinline__ void gload_lds16(const void* g, void* l) {
    __builtin_amdgcn_global_load_lds(
        (const __attribute__((address_space(1))) unsigned int*)g,
        (__attribute__((address_space(3))) unsigned int*)l, 16, 0, 0);
}

// ws layout: sbf[BN*DD] bf16 | mag[BN] f32 | nes[BN] f32 | sum f32 | cnt u32 |
//            cls_cnt[64] | cls_start[64] | cls_list[BN]

__global__ __launch_bounds__(256)
void prep_kernel(const float* __restrict__ score, unsigned short* __restrict__ sbf,
                 float* __restrict__ mag) {
    int row  = blockIdx.x * 4 + (threadIdx.x >> 6);
    int lane = threadIdx.x & 63;
    float2 v = *reinterpret_cast<const float2*>(score + (size_t)row * DD + lane * 2);
    float s = v.x * v.x + v.y * v.y;
    #pragma unroll
    for (int off = 32; off; off >>= 1) s += __shfl_xor(s, off);
    ushort2 u; u.x = f2bf(v.x); u.y = f2bf(v.y);
    *reinterpret_cast<ushort2*>(sbf + (size_t)row * DD + lane * 2) = u;
    if (lane == 0) mag[row] = s;
}

__global__ __launch_bounds__(256)
void bucket_kernel(const int* __restrict__ target,
                   int* __restrict__ cls_cnt, int* __restrict__ cls_start,
                   int* __restrict__ cls_list) {
    __shared__ int hist[NCLS];
    __shared__ int offs[NCLS];
    int tid = threadIdx.x;
    if (tid < NCLS) hist[tid] = 0;
    __syncthreads();
    for (int i = tid; i < BN; i += 256) atomicAdd(&hist[target[i]], 1);
    __syncthreads();
    if (tid == 0) {
        int run = 0;
        for (int c = 0; c < NCLS; ++c) {
            cls_cnt[c] = hist[c];
            cls_start[c] = run;
            offs[c] = run;
            run += hist[c];
        }
    }
    __syncthreads();
    for (int i = tid; i < BN; i += 256) {
        int p = atomicAdd(&offs[target[i]], 1);
        cls_list[p] = i;
    }
}

// 128x128 tile, 4 waves (2x2), each wave 64x64 via 4x4 fragments of 16x16x32 bf16.
// LDS layout: linear row-major [128][128] bf16 per tile, but CONTENT is
// chunk-swizzled (16B chunk c of row r holds global chunk c^(r&7)) via
// pre-swizzled global_load_lds source; reads apply the same XOR.
__global__ __launch_bounds__(256)
void nes_kernel(const unsigned short* __restrict__ sbf, const int* __restrict__ target,
                const float* __restrict__ alphap, const float* __restrict__ mag,
                float* __restrict__ nes) {
    __shared__ __align__(16) unsigned short lds[2 * 128 * 128];   // A | B, 64 KB
    const int tid = threadIdx.x;
    const int w = tid >> 6, lane = tid & 63;
    const int lhi = lane >> 4, llo = lane & 15;
    const int i0 = blockIdx.x * 128, j0 = blockIdx.y * 128;

    // stage: each wave 32 rows per tile, 8 issues of 4 rows (64 lanes x 16B)
    #pragma unroll
    for (int t = 0; t < 8; ++t) {
        int rl = w * 32 + t * 4 + lhi;              // local row this lane feeds
        int ch = llo ^ (rl & 7);                    // pre-swizzled source chunk
        const unsigned short* srcA = sbf + (size_t)(i0 + rl) * DD + ch * 8;
        const unsigned short* srcB = sbf + (size_t)(j0 + rl) * DD + ch * 8;
        gload_lds16(srcA, lds + (w * 32 + t * 4) * 128);
        gload_lds16(srcB, lds + 128 * 128 + (w * 32 + t * 4) * 128);
    }
    __syncthreads();

    const int wr = w >> 1, wc = w & 1;
    f32x4 acc[4][4] = {};
    #pragma unroll
    for (int kk = 0; kk < 4; ++kk) {
        short8 a[4], b[4];
        #pragma unroll
        for (int m = 0; m < 4; ++m) {
            int r = wr * 64 + m * 16 + llo;
            int ch = (kk * 4 + lhi) ^ (r & 7);
            a[m] = *reinterpret_cast<const short8*>(lds + r * 128 + ch * 8);
        }
        #pragma unroll
        for (int n = 0; n < 4; ++n) {
            int r = wc * 64 + n * 16 + llo;
            int ch = (kk * 4 + lhi) ^ (r & 7);
            b[n] = *reinterpret_cast<const short8*>(lds + 128 * 128 + r * 128 + ch * 8);
        }
        #pragma unroll
        for (int m = 0; m < 4; ++m)
            #pragma unroll
            for (int n = 0; n < 4; ++n)
                acc[m][n] = __builtin_amdgcn_mfma_f32_16x16x32_bf16(a[m], b[n], acc[m][n], 0, 0, 0);
    }

    // epilogue: d2 -> dist -> masked exp -> per-row sums (C/D: col=lane&15, row=lhi*4+reg)
    const float alpha = alphap[0];
    float mj[4]; int tj[4];
    #pragma unroll
    for (int n = 0; n < 4; ++n) {
        int j = j0 + wc * 64 + n * 16 + llo;
        mj[n] = mag[j]; tj[n] = target[j];
    }
    #pragma unroll
    for (int m = 0; m < 4; ++m) {
        #pragma unroll
        for (int rg = 0; rg < 4; ++rg) {
            int i = i0 + wr * 64 + m * 16 + lhi * 4 + rg;
            float mi = mag[i];
            int ti = target[i];
            float rs = 0.f;
            #pragma unroll
            for (int n = 0; n < 4; ++n) {
                float d2 = fmaxf(mi + mj[n] - 2.0f * acc[m][n][rg], 0.0f);
                float dist = sqrtf(d2);
                rs += (ti != tj[n]) ? __expf(alpha - dist) : 0.0f;
            }
            rs += __shfl_xor(rs, 1);
            rs += __shfl_xor(rs, 2);
            rs += __shfl_xor(rs, 4);
            rs += __shfl_xor(rs, 8);
            if (llo == 0) atomicAdd(&nes[i], rs);
        }
    }
}

// grid (NCLS, PSPLIT); one 16-lane group per pair, coalesced row loads,
// exact fp32 dots for the ~C(n_c,2) positive pairs of each class.
__global__ __launch_bounds__(256)
void pos_kernel(const float* __restrict__ score, const float* __restrict__ mag,
                const float* __restrict__ nes,
                const int* __restrict__ cls_cnt, const int* __restrict__ cls_start,
                const int* __restrict__ cls_list,
                float* __restrict__ sum, unsigned int* __restrict__ cntp) {
    const int c = blockIdx.x;
    const int n = cls_cnt[c], s0 = cls_start[c];
    const int tid = threadIdx.x;
    const int grp = tid >> 4, llo = tid & 15;       // 16 groups per block
    const int g0 = blockIdx.y * 16 + grp;           // global group id for this class
    const int nG = 16 * PSPLIT;                     // groups striding this class
    const int nn = n * n;
    float s = 0.f;
    unsigned int cc = 0;
    for (int p = g0; p < nn; p += nG) {
        int a = p / n, b = p - a * n;
        if (b <= a) continue;
        int i = cls_list[s0 + a], j = cls_list[s0 + b];
        const float4* ra = reinterpret_cast<const float4*>(score + (size_t)i * DD) + llo * 2;
        const float4* rb = reinterpret_cast<const float4*>(score + (size_t)j * DD) + llo * 2;
        float4 x0 = ra[0], x1 = ra[1];
        float4 y0 = rb[0], y1 = rb[1];
        float dot = x0.x * y0.x + x0.y * y0.y + x0.z * y0.z + x0.w * y0.w
                  + x1.x * y1.x + x1.y * y1.y + x1.z * y1.z + x1.w * y1.w;
        dot += __shfl_xor(dot, 1);
        dot += __shfl_xor(dot, 2);
        dot += __shfl_xor(dot, 4);
        dot += __shfl_xor(dot, 8);
        if (llo == 0) {
            float d2 = fmaxf(mag[i] + mag[j] - 2.0f * dot, 0.0f);
            float dist = sqrtf(d2);
            float t = __logf(nes[i] + nes[j]) + dist;
            if (t > 0.f) s += t * t;
            cc++;
        }
    }
    #pragma unroll
    for (int off = 1; off < 64; off <<= 1) {
        s += __shfl_xor(s, off);
        cc += __shfl_xor(cc, off);
    }
    if ((tid & 63) == 0) { atomicAdd(sum, s); atomicAdd(cntp, cc); }
}

__global__ void finalize_kernel(const float* __restrict__ sum,
                                const unsigned int* __restrict__ cnt,
                                float* __restrict__ out) {
    out[0] = sum[0] / (2.0f * (float)cnt[0]);
}

extern "C" void kernel_launch(void* const* d_in, const int* in_sizes, int n_in,
                              void* d_out, int out_size, void* d_ws, size_t ws_size,
                              hipStream_t stream) {
    const float* score  = (const float*)d_in[0];
    const int*   target = (const int*)d_in[1];
    const float* alpha  = (const float*)d_in[2];
    float* out = (float*)d_out;

    unsigned short* sbf = (unsigned short*)d_ws;
    float* mag = (float*)((char*)d_ws + (size_t)BN * DD * 2);
    float* nes = mag + BN;
    float* sum = nes + BN;
    unsigned int* cnt = (unsigned int*)(sum + 1);
    int* cls_cnt   = (int*)(cnt + 1);
    int* cls_start = cls_cnt + NCLS;
    int* cls_list  = cls_start + NCLS;

    hipMemsetAsync(nes, 0, (BN + 2) * sizeof(float), stream);   // nes + sum + cnt

    prep_kernel<<<BN / 4, 256, 0, stream>>>(score, sbf, mag);
    bucket_kernel<<<1, 256, 0, stream>>>(target, cls_cnt, cls_start, cls_list);
    dim3 g(BN / 128, BN / 128);
    nes_kernel<<<g, 256, 0, stream>>>(sbf, target, alpha, mag, nes);
    pos_kernel<<<dim3(NCLS, PSPLIT), 256, 0, stream>>>(score, mag, nes,
                                                       cls_cnt, cls_start, cls_list, sum, cnt);
    finalize_kernel<<<1, 1, 0, stream>>>(sum, cnt, out);
}

// Round 4
// 112.550 us; speedup vs baseline: 1.8299x; 1.8299x over previous
//
#include <hip/hip_runtime.h>
#include <math.h>

#define BN 4096
#define DD 128
#define NCLS 64
#define PSPLIT 16
#define NPOSB (NCLS * PSPLIT)   // 1024 pos blocks
#define NJB 32                  // j-block partial count for nes

typedef __attribute__((ext_vector_type(8))) short short8;
typedef __attribute__((ext_vector_type(4))) float f32x4;

__device__ __forceinline__ unsigned short f2bf(float f) {
    unsigned int u = __float_as_uint(f);
    u += 0x7FFFu + ((u >> 16) & 1u);   // RNE; inputs are finite normals
    return (unsigned short)(u >> 16);
}

__device__ __forceinline__ void gload_lds16(const void* g, void* l) {
    __builtin_amdgcn_global_load_lds(
        (const __attribute__((address_space(1))) unsigned int*)g,
        (__attribute__((address_space(3))) unsigned int*)l, 16, 0, 0);
}

// ws layout:
//   sbf[BN*DD] bf16 | mag[BN] f32 | nes[BN] f32 | nes_part[NJB][BN] f32 |
//   part_sum[NPOSB] f32 | part_cnt[NPOSB] u32 |
//   cls_cnt[64] | cls_start[64] | cls_list[BN]

__global__ __launch_bounds__(256)
void prep_kernel(const float* __restrict__ score, unsigned short* __restrict__ sbf,
                 float* __restrict__ mag) {
    int row  = blockIdx.x * 4 + (threadIdx.x >> 6);
    int lane = threadIdx.x & 63;
    float2 v = *reinterpret_cast<const float2*>(score + (size_t)row * DD + lane * 2);
    float s = v.x * v.x + v.y * v.y;
    #pragma unroll
    for (int off = 32; off; off >>= 1) s += __shfl_xor(s, off);
    ushort2 u; u.x = f2bf(v.x); u.y = f2bf(v.y);
    *reinterpret_cast<ushort2*>(sbf + (size_t)row * DD + lane * 2) = u;
    if (lane == 0) mag[row] = s;
}

__global__ __launch_bounds__(256)
void bucket_kernel(const int* __restrict__ target,
                   int* __restrict__ cls_cnt, int* __restrict__ cls_start,
                   int* __restrict__ cls_list) {
    __shared__ int hist[NCLS];
    __shared__ int offs[NCLS];
    int tid = threadIdx.x;
    if (tid < NCLS) hist[tid] = 0;
    __syncthreads();
    for (int i = tid; i < BN; i += 256) atomicAdd(&hist[target[i]], 1);
    __syncthreads();
    if (tid == 0) {
        int run = 0;
        for (int c = 0; c < NCLS; ++c) {
            cls_cnt[c] = hist[c];
            cls_start[c] = run;
            offs[c] = run;
            run += hist[c];
        }
    }
    __syncthreads();
    for (int i = tid; i < BN; i += 256) {
        int p = atomicAdd(&offs[target[i]], 1);
        cls_list[p] = i;
    }
}

// 128x128 tile, 4 waves (2x2), each wave 64x64 via 4x4 fragments of 16x16x32 bf16.
// LDS content chunk-swizzled via pre-swizzled global_load_lds source (rule 21).
// Row sums leave through LDS + plain coalesced stores — NO global atomics.
__global__ __launch_bounds__(256)
void nes_kernel(const unsigned short* __restrict__ sbf, const int* __restrict__ target,
                const float* __restrict__ alphap, const float* __restrict__ mag,
                float* __restrict__ nes_part) {
    __shared__ __align__(16) unsigned short lds[2 * 128 * 128];   // A | B, 64 KB
    __shared__ float rowsum[2][128];
    const int tid = threadIdx.x;
    const int w = tid >> 6, lane = tid & 63;
    const int lhi = lane >> 4, llo = lane & 15;
    const int i0 = blockIdx.x * 128, j0 = blockIdx.y * 128;
    const int jb = blockIdx.y;

    #pragma unroll
    for (int t = 0; t < 8; ++t) {
        int rl = w * 32 + t * 4 + lhi;              // local row this lane feeds
        int ch = llo ^ (rl & 7);                    // pre-swizzled source chunk
        const unsigned short* srcA = sbf + (size_t)(i0 + rl) * DD + ch * 8;
        const unsigned short* srcB = sbf + (size_t)(j0 + rl) * DD + ch * 8;
        gload_lds16(srcA, lds + (w * 32 + t * 4) * 128);
        gload_lds16(srcB, lds + 128 * 128 + (w * 32 + t * 4) * 128);
    }
    __syncthreads();

    const int wr = w >> 1, wc = w & 1;
    f32x4 acc[4][4] = {};
    #pragma unroll
    for (int kk = 0; kk < 4; ++kk) {
        short8 a[4], b[4];
        #pragma unroll
        for (int m = 0; m < 4; ++m) {
            int r = wr * 64 + m * 16 + llo;
            int ch = (kk * 4 + lhi) ^ (r & 7);
            a[m] = *reinterpret_cast<const short8*>(lds + r * 128 + ch * 8);
        }
        #pragma unroll
        for (int n = 0; n < 4; ++n) {
            int r = wc * 64 + n * 16 + llo;
            int ch = (kk * 4 + lhi) ^ (r & 7);
            b[n] = *reinterpret_cast<const short8*>(lds + 128 * 128 + r * 128 + ch * 8);
        }
        #pragma unroll
        for (int m = 0; m < 4; ++m)
            #pragma unroll
            for (int n = 0; n < 4; ++n)
                acc[m][n] = __builtin_amdgcn_mfma_f32_16x16x32_bf16(a[m], b[n], acc[m][n], 0, 0, 0);
    }

    // epilogue: d2 -> dist -> masked exp -> per-row sums (C/D: col=lane&15, row=lhi*4+reg)
    const float alpha = alphap[0];
    float mj[4]; int tj[4];
    #pragma unroll
    for (int n = 0; n < 4; ++n) {
        int j = j0 + wc * 64 + n * 16 + llo;
        mj[n] = mag[j]; tj[n] = target[j];
    }
    #pragma unroll
    for (int m = 0; m < 4; ++m) {
        #pragma unroll
        for (int rg = 0; rg < 4; ++rg) {
            int li = wr * 64 + m * 16 + lhi * 4 + rg;   // local row
            int i = i0 + li;
            float mi = mag[i];
            int ti = target[i];
            float rs = 0.f;
            #pragma unroll
            for (int n = 0; n < 4; ++n) {
                float d2 = fmaxf(mi + mj[n] - 2.0f * acc[m][n][rg], 0.0f);
                float dist = sqrtf(d2);
                rs += (ti != tj[n]) ? __expf(alpha - dist) : 0.0f;
            }
            rs += __shfl_xor(rs, 1);
            rs += __shfl_xor(rs, 2);
            rs += __shfl_xor(rs, 4);
            rs += __shfl_xor(rs, 8);
            if (llo == 0) rowsum[wc][li] = rs;
        }
    }
    __syncthreads();
    if (tid < 128)
        nes_part[(size_t)jb * BN + i0 + tid] = rowsum[0][tid] + rowsum[1][tid];
}

__global__ __launch_bounds__(256)
void nes_reduce_kernel(const float* __restrict__ nes_part, float* __restrict__ nes) {
    int t = blockIdx.x * 256 + threadIdx.x;   // 0..BN-1
    float s = 0.f;
    #pragma unroll
    for (int k = 0; k < NJB; ++k) s += nes_part[(size_t)k * BN + t];
    nes[t] = s;
}

// grid (NCLS, PSPLIT); one 16-lane group per pair, coalesced row loads,
// exact fp32 dots. Per-block partial via LDS — NO global atomics.
__global__ __launch_bounds__(256)
void pos_kernel(const float* __restrict__ score, const float* __restrict__ mag,
                const float* __restrict__ nes,
                const int* __restrict__ cls_cnt, const int* __restrict__ cls_start,
                const int* __restrict__ cls_list,
                float* __restrict__ part_sum, unsigned int* __restrict__ part_cnt) {
    __shared__ float ssum[4];
    __shared__ unsigned int scnt[4];
    const int c = blockIdx.x;
    const int n = cls_cnt[c], s0 = cls_start[c];
    const int tid = threadIdx.x;
    const int grp = tid >> 4, llo = tid & 15;
    const int g0 = blockIdx.y * 16 + grp;
    const int nG = 16 * PSPLIT;
    const int nn = n * n;
    float s = 0.f;
    unsigned int cc = 0;
    for (int p = g0; p < nn; p += nG) {
        int a = p / n, b = p - a * n;
        if (b <= a) continue;
        int i = cls_list[s0 + a], j = cls_list[s0 + b];
        const float4* ra = reinterpret_cast<const float4*>(score + (size_t)i * DD) + llo * 2;
        const float4* rb = reinterpret_cast<const float4*>(score + (size_t)j * DD) + llo * 2;
        float4 x0 = ra[0], x1 = ra[1];
        float4 y0 = rb[0], y1 = rb[1];
        float dot = x0.x * y0.x + x0.y * y0.y + x0.z * y0.z + x0.w * y0.w
                  + x1.x * y1.x + x1.y * y1.y + x1.z * y1.z + x1.w * y1.w;
        dot += __shfl_xor(dot, 1);
        dot += __shfl_xor(dot, 2);
        dot += __shfl_xor(dot, 4);
        dot += __shfl_xor(dot, 8);
        if (llo == 0) {
            float d2 = fmaxf(mag[i] + mag[j] - 2.0f * dot, 0.0f);
            float dist = sqrtf(d2);
            float t = __logf(nes[i] + nes[j]) + dist;
            if (t > 0.f) s += t * t;
            cc++;
        }
    }
    #pragma unroll
    for (int off = 1; off < 64; off <<= 1) {
        s += __shfl_xor(s, off);
        cc += __shfl_xor(cc, off);
    }
    if ((tid & 63) == 0) { ssum[tid >> 6] = s; scnt[tid >> 6] = cc; }
    __syncthreads();
    if (tid == 0) {
        int bid = blockIdx.y * NCLS + blockIdx.x;
        part_sum[bid] = ssum[0] + ssum[1] + ssum[2] + ssum[3];
        part_cnt[bid] = scnt[0] + scnt[1] + scnt[2] + scnt[3];
    }
}

__global__ __launch_bounds__(256)
void finalize_kernel(const float* __restrict__ part_sum,
                     const unsigned int* __restrict__ part_cnt,
                     float* __restrict__ out) {
    __shared__ float fs[4];
    __shared__ unsigned int fc[4];
    int tid = threadIdx.x;
    float s = 0.f;
    unsigned int c = 0;
    #pragma unroll
    for (int k = 0; k < NPOSB / 256; ++k) {
        s += part_sum[k * 256 + tid];
        c += part_cnt[k * 256 + tid];
    }
    #pragma unroll
    for (int off = 1; off < 64; off <<= 1) {
        s += __shfl_xor(s, off);
        c += __shfl_xor(c, off);
    }
    if ((tid & 63) == 0) { fs[tid >> 6] = s; fc[tid >> 6] = c; }
    __syncthreads();
    if (tid == 0) {
        float S = fs[0] + fs[1] + fs[2] + fs[3];
        float C = (float)(fc[0] + fc[1] + fc[2] + fc[3]);
        out[0] = S / (2.0f * C);
    }
}

extern "C" void kernel_launch(void* const* d_in, const int* in_sizes, int n_in,
                              void* d_out, int out_size, void* d_ws, size_t ws_size,
                              hipStream_t stream) {
    const float* score  = (const float*)d_in[0];
    const int*   target = (const int*)d_in[1];
    const float* alpha  = (const float*)d_in[2];
    float* out = (float*)d_out;

    unsigned short* sbf = (unsigned short*)d_ws;
    float* mag      = (float*)((char*)d_ws + (size_t)BN * DD * 2);
    float* nes      = mag + BN;
    float* nes_part = nes + BN;
    float* part_sum = nes_part + (size_t)NJB * BN;
    unsigned int* part_cnt = (unsigned int*)(part_sum + NPOSB);
    int* cls_cnt   = (int*)(part_cnt + NPOSB);
    int* cls_start = cls_cnt + NCLS;
    int* cls_list  = cls_start + NCLS;

    prep_kernel<<<BN / 4, 256, 0, stream>>>(score, sbf, mag);
    bucket_kernel<<<1, 256, 0, stream>>>(target, cls_cnt, cls_start, cls_list);
    dim3 g(BN / 128, BN / 128);
    nes_kernel<<<g, 256, 0, stream>>>(sbf, target, alpha, mag, nes_part);
    nes_reduce_kernel<<<BN / 256, 256, 0, stream>>>(nes_part, nes);
    pos_kernel<<<dim3(NCLS, PSPLIT), 256, 0, stream>>>(score, mag, nes,
                                                       cls_cnt, cls_start, cls_list,
                                                       part_sum, part_cnt);
    finalize_kernel<<<1, 256, 0, stream>>>(part_sum, part_cnt, out);
}

// Round 5
// 109.806 us; speedup vs baseline: 1.8757x; 1.0250x over previous
//
#include <hip/hip_runtime.h>
#include <math.h>

#define BN 4096
#define DD 128
#define NCLS 64
#define PSPLIT 16
#define NPOSB (NCLS * PSPLIT)   // 1024 pos blocks
#define NJB 32                  // partials per row (j-tile count)

typedef __attribute__((ext_vector_type(8))) short short8;
typedef __attribute__((ext_vector_type(4))) float f32x4;

__device__ __forceinline__ unsigned short f2bf(float f) {
    unsigned int u = __float_as_uint(f);
    u += 0x7FFFu + ((u >> 16) & 1u);   // RNE; inputs are finite normals
    return (unsigned short)(u >> 16);
}

__device__ __forceinline__ void gload_lds16(const void* g, void* l) {
    __builtin_amdgcn_global_load_lds(
        (const __attribute__((address_space(1))) unsigned int*)g,
        (__attribute__((address_space(3))) unsigned int*)l, 16, 0, 0);
}

// ws layout:
//   sbf[BN*DD] bf16 | mag[BN] f32 | nes_part[BN][NJB] f32 |
//   part_sum[NPOSB] f32 | part_cnt[NPOSB] u32 |
//   cls_cnt[64] | cls_start[64] | cls_list[BN]

// grid 1025: blocks 0..1023 = prep (bf16 cast + row norms), block 1024 = bucket
__global__ __launch_bounds__(256)
void prep_bucket_kernel(const float* __restrict__ score, const int* __restrict__ target,
                        unsigned short* __restrict__ sbf, float* __restrict__ mag,
                        int* __restrict__ cls_cnt, int* __restrict__ cls_start,
                        int* __restrict__ cls_list) {
    __shared__ int hist[NCLS];
    __shared__ int offs[NCLS];
    const int tid = threadIdx.x;
    if (blockIdx.x < BN / 4) {
        int row  = blockIdx.x * 4 + (tid >> 6);
        int lane = tid & 63;
        float2 v = *reinterpret_cast<const float2*>(score + (size_t)row * DD + lane * 2);
        float s = v.x * v.x + v.y * v.y;
        #pragma unroll
        for (int off = 32; off; off >>= 1) s += __shfl_xor(s, off);
        ushort2 u; u.x = f2bf(v.x); u.y = f2bf(v.y);
        *reinterpret_cast<ushort2*>(sbf + (size_t)row * DD + lane * 2) = u;
        if (lane == 0) mag[row] = s;
    } else {
        if (tid < NCLS) hist[tid] = 0;
        __syncthreads();
        for (int i = tid; i < BN; i += 256) atomicAdd(&hist[target[i]], 1);
        __syncthreads();
        if (tid == 0) {
            int run = 0;
            for (int c = 0; c < NCLS; ++c) {
                cls_cnt[c] = hist[c];
                cls_start[c] = run;
                offs[c] = run;
                run += hist[c];
            }
        }
        __syncthreads();
        for (int i = tid; i < BN; i += 256) {
            int p = atomicAdd(&offs[target[i]], 1);
            cls_list[p] = i;
        }
    }
}

// Upper-triangle 128x128 tiles only (jb >= ib). Off-diagonal tiles emit BOTH
// row-sums (partial jb for the i-rows) and col-sums (partial ib for the
// j-rows); diagonal tiles emit row-sums only and reuse the A-half of LDS for B.
// LDS content chunk-swizzled via pre-swizzled global_load_lds source (rule 21).
__global__ __launch_bounds__(256)
void nes_kernel(const unsigned short* __restrict__ sbf, const int* __restrict__ target,
                const float* __restrict__ alphap, const float* __restrict__ mag,
                float* __restrict__ nes_part) {
    const int ib = blockIdx.x, jb = blockIdx.y;
    if (jb < ib) return;
    __shared__ __align__(16) unsigned short lds[2 * 128 * 128];   // A | B, 64 KB
    __shared__ float rowsum[2][128];   // [wc][local row]
    __shared__ float colsum[2][128];   // [wr][local col]
    const int tid = threadIdx.x;
    const int w = tid >> 6, lane = tid & 63;
    const int lhi = lane >> 4, llo = lane & 15;
    const int i0 = ib * 128, j0 = jb * 128;
    const bool diag = (ib == jb);

    #pragma unroll
    for (int t = 0; t < 8; ++t) {
        int rl = w * 32 + t * 4 + lhi;              // local row this lane feeds
        int ch = llo ^ (rl & 7);                    // pre-swizzled source chunk
        gload_lds16(sbf + (size_t)(i0 + rl) * DD + ch * 8, lds + (w * 32 + t * 4) * 128);
        if (!diag)
            gload_lds16(sbf + (size_t)(j0 + rl) * DD + ch * 8,
                        lds + 128 * 128 + (w * 32 + t * 4) * 128);
    }
    __syncthreads();

    const unsigned short* bbase = diag ? lds : (lds + 128 * 128);
    const int wr = w >> 1, wc = w & 1;
    f32x4 acc[4][4] = {};
    #pragma unroll
    for (int kk = 0; kk < 4; ++kk) {
        short8 a[4], b[4];
        #pragma unroll
        for (int m = 0; m < 4; ++m) {
            int r = wr * 64 + m * 16 + llo;
            int ch = (kk * 4 + lhi) ^ (r & 7);
            a[m] = *reinterpret_cast<const short8*>(lds + r * 128 + ch * 8);
        }
        #pragma unroll
        for (int n = 0; n < 4; ++n) {
            int r = wc * 64 + n * 16 + llo;
            int ch = (kk * 4 + lhi) ^ (r & 7);
            b[n] = *reinterpret_cast<const short8*>(bbase + r * 128 + ch * 8);
        }
        #pragma unroll
        for (int m = 0; m < 4; ++m)
            #pragma unroll
            for (int n = 0; n < 4; ++n)
                acc[m][n] = __builtin_amdgcn_mfma_f32_16x16x32_bf16(a[m], b[n], acc[m][n], 0, 0, 0);
    }

    // epilogue (C/D: col = lane&15, row = lhi*4+reg)
    const float alpha = alphap[0];
    float mj[4]; int tj[4];
    #pragma unroll
    for (int n = 0; n < 4; ++n) {
        int j = j0 + wc * 64 + n * 16 + llo;
        mj[n] = mag[j]; tj[n] = target[j];
    }
    float cs[4] = {0.f, 0.f, 0.f, 0.f};
    #pragma unroll
    for (int m = 0; m < 4; ++m) {
        #pragma unroll
        for (int rg = 0; rg < 4; ++rg) {
            int li = wr * 64 + m * 16 + lhi * 4 + rg;   // local row
            int i = i0 + li;
            float mi = mag[i];
            int ti = target[i];
            float rs = 0.f;
            #pragma unroll
            for (int n = 0; n < 4; ++n) {
                float d2 = fmaxf(mi + mj[n] - 2.0f * acc[m][n][rg], 0.0f);
                float dist = sqrtf(d2);
                float e = (ti != tj[n]) ? __expf(alpha - dist) : 0.0f;
                rs += e;
                cs[n] += e;
            }
            rs += __shfl_xor(rs, 1);
            rs += __shfl_xor(rs, 2);
            rs += __shfl_xor(rs, 4);
            rs += __shfl_xor(rs, 8);
            if (llo == 0) rowsum[wc][li] = rs;
        }
    }
    #pragma unroll
    for (int n = 0; n < 4; ++n) {
        cs[n] += __shfl_xor(cs[n], 16);
        cs[n] += __shfl_xor(cs[n], 32);
        if (lhi == 0) colsum[wr][wc * 64 + n * 16 + llo] = cs[n];
    }
    __syncthreads();
    if (tid < 128) {
        nes_part[(size_t)(i0 + tid) * NJB + jb] = rowsum[0][tid] + rowsum[1][tid];
        if (!diag)
            nes_part[(size_t)(j0 + tid) * NJB + ib] = colsum[0][tid] + colsum[1][tid];
    }
}

// grid (NCLS, PSPLIT); one 16-lane group per pair: direct-diff d2 + inline
// reduction of the 32 nes partials for i and j (rides the same shfl tree).
__global__ __launch_bounds__(256)
void pos_kernel(const float* __restrict__ score, const float* __restrict__ nes_part,
                const int* __restrict__ cls_cnt, const int* __restrict__ cls_start,
                const int* __restrict__ cls_list,
                float* __restrict__ part_sum, unsigned int* __restrict__ part_cnt) {
    __shared__ float ssum[4];
    __shared__ unsigned int scnt[4];
    const int c = blockIdx.x;
    const int n = cls_cnt[c], s0 = cls_start[c];
    const int tid = threadIdx.x;
    const int grp = tid >> 4, llo = tid & 15;
    const int g0 = blockIdx.y * 16 + grp;
    const int nG = 16 * PSPLIT;
    const int nn = n * n;
    float s = 0.f;
    unsigned int cc = 0;
    for (int p = g0; p < nn; p += nG) {
        int a = p / n, b = p - a * n;
        if (b <= a) continue;
        int i = cls_list[s0 + a], j = cls_list[s0 + b];
        const float4* ra = reinterpret_cast<const float4*>(score + (size_t)i * DD) + llo * 2;
        const float4* rb = reinterpret_cast<const float4*>(score + (size_t)j * DD) + llo * 2;
        float4 x0 = ra[0], x1 = ra[1];
        float4 y0 = rb[0], y1 = rb[1];
        float dx;
        float d2 = 0.f;
        dx = x0.x - y0.x; d2 += dx * dx;
        dx = x0.y - y0.y; d2 += dx * dx;
        dx = x0.z - y0.z; d2 += dx * dx;
        dx = x0.w - y0.w; d2 += dx * dx;
        dx = x1.x - y1.x; d2 += dx * dx;
        dx = x1.y - y1.y; d2 += dx * dx;
        dx = x1.z - y1.z; d2 += dx * dx;
        dx = x1.w - y1.w; d2 += dx * dx;
        float2 pi = *reinterpret_cast<const float2*>(nes_part + (size_t)i * NJB + llo * 2);
        float2 pj = *reinterpret_cast<const float2*>(nes_part + (size_t)j * NJB + llo * 2);
        float ni = pi.x + pi.y;
        float nj = pj.x + pj.y;
        #pragma unroll
        for (int off = 1; off < 16; off <<= 1) {
            d2 += __shfl_xor(d2, off);
            ni += __shfl_xor(ni, off);
            nj += __shfl_xor(nj, off);
        }
        if (llo == 0) {
            float dist = sqrtf(d2);
            float t = __logf(ni + nj) + dist;
            if (t > 0.f) s += t * t;
            cc++;
        }
    }
    #pragma unroll
    for (int off = 1; off < 64; off <<= 1) {
        s += __shfl_xor(s, off);
        cc += __shfl_xor(cc, off);
    }
    if ((tid & 63) == 0) { ssum[tid >> 6] = s; scnt[tid >> 6] = cc; }
    __syncthreads();
    if (tid == 0) {
        int bid = blockIdx.y * NCLS + blockIdx.x;
        part_sum[bid] = ssum[0] + ssum[1] + ssum[2] + ssum[3];
        part_cnt[bid] = scnt[0] + scnt[1] + scnt[2] + scnt[3];
    }
}

__global__ __launch_bounds__(256)
void finalize_kernel(const float* __restrict__ part_sum,
                     const unsigned int* __restrict__ part_cnt,
                     float* __restrict__ out) {
    __shared__ float fs[4];
    __shared__ unsigned int fc[4];
    int tid = threadIdx.x;
    float s = 0.f;
    unsigned int c = 0;
    #pragma unroll
    for (int k = 0; k < NPOSB / 256; ++k) {
        s += part_sum[k * 256 + tid];
        c += part_cnt[k * 256 + tid];
    }
    #pragma unroll
    for (int off = 1; off < 64; off <<= 1) {
        s += __shfl_xor(s, off);
        c += __shfl_xor(c, off);
    }
    if ((tid & 63) == 0) { fs[tid >> 6] = s; fc[tid >> 6] = c; }
    __syncthreads();
    if (tid == 0) {
        float S = fs[0] + fs[1] + fs[2] + fs[3];
        float C = (float)(fc[0] + fc[1] + fc[2] + fc[3]);
        out[0] = S / (2.0f * C);
    }
}

extern "C" void kernel_launch(void* const* d_in, const int* in_sizes, int n_in,
                              void* d_out, int out_size, void* d_ws, size_t ws_size,
                              hipStream_t stream) {
    const float* score  = (const float*)d_in[0];
    const int*   target = (const int*)d_in[1];
    const float* alpha  = (const float*)d_in[2];
    float* out = (float*)d_out;

    unsigned short* sbf = (unsigned short*)d_ws;
    float* mag      = (float*)((char*)d_ws + (size_t)BN * DD * 2);
    float* nes_part = mag + BN;
    float* part_sum = nes_part + (size_t)BN * NJB;
    unsigned int* part_cnt = (unsigned int*)(part_sum + NPOSB);
    int* cls_cnt   = (int*)(part_cnt + NPOSB);
    int* cls_start = cls_cnt + NCLS;
    int* cls_list  = cls_start + NCLS;

    prep_bucket_kernel<<<BN / 4 + 1, 256, 0, stream>>>(score, target, sbf, mag,
                                                       cls_cnt, cls_start, cls_list);
    dim3 g(BN / 128, BN / 128);
    nes_kernel<<<g, 256, 0, stream>>>(sbf, target, alpha, mag, nes_part);
    pos_kernel<<<dim3(NCLS, PSPLIT), 256, 0, stream>>>(score, nes_part,
                                                       cls_cnt, cls_start, cls_list,
                                                       part_sum, part_cnt);
    finalize_kernel<<<1, 256, 0, stream>>>(part_sum, part_cnt, out);
}